// Round 9
// baseline (426.974 us; speedup 1.0000x reference)
//
#include <hip/hip_runtime.h>
#include <cstdint>
#include <cstddef>

typedef unsigned short u16;
typedef short short8 __attribute__((ext_vector_type(8)));
typedef float f32x4 __attribute__((ext_vector_type(4)));

#define B_   2
#define T_   2048
#define H_   16
#define HID_ 2048
#define DQK_ 192
#define DV_  128
#define AW_  3072   // fused a-proj output width (q_a 1536 | kv_raw 1536)

__device__ __forceinline__ float bf2f(u16 u) {
  unsigned int v = ((unsigned int)u) << 16;
  return __builtin_bit_cast(float, v);
}
__device__ __forceinline__ u16 f2bf(float f) {
  unsigned int u = __builtin_bit_cast(unsigned int, f);
  u += 0x7fff + ((u >> 16) & 1);   // round-to-nearest-even
  return (u16)(u >> 16);
}
__device__ __forceinline__ void load_lds16(const void* g, void* l) {
  __builtin_amdgcn_global_load_lds((const __attribute__((address_space(1))) void*)g,
                                   (__attribute__((address_space(3))) void*)l, 16, 0, 0);
}

// ---------------- cast f32 -> bf16 (8 elems/thread) ----------------
__global__ __launch_bounds__(256) void cast_f32_bf16(const float* __restrict__ x,
                                                     u16* __restrict__ y) {
  size_t i = ((size_t)blockIdx.x * 256 + threadIdx.x) * 8;
  float4 a = *(const float4*)&x[i];
  float4 b = *(const float4*)&x[i + 4];
  u16 r[8];
  r[0] = f2bf(a.x); r[1] = f2bf(a.y); r[2] = f2bf(a.z); r[3] = f2bf(a.w);
  r[4] = f2bf(b.x); r[5] = f2bf(b.y); r[6] = f2bf(b.z); r[7] = f2bf(b.w);
  *(uint4*)&y[i] = *(const uint4*)&r[0];
}

// ---------------- W (K x N) f32  ->  Wt (N x K) bf16 ----------------
__global__ __launch_bounds__(256) void transpose_cast_k(const float* __restrict__ W,
                                                        u16* __restrict__ Wt,
                                                        int K, int N) {
  __shared__ u16 tile[32][33];
  int n0 = blockIdx.x * 32, k0 = blockIdx.y * 32;
  int tx = threadIdx.x & 31, ty = threadIdx.x >> 5;
#pragma unroll
  for (int i = 0; i < 32; i += 8)
    tile[ty + i][tx] = f2bf(W[(size_t)(k0 + ty + i) * N + n0 + tx]);
  __syncthreads();
#pragma unroll
  for (int i = 0; i < 32; i += 8)
    Wt[(size_t)(n0 + ty + i) * K + k0 + tx] = tile[tx][ty + i];
}

// ---------------- RMSNorm over rows (bf16 in/out, f32 weight) ----------------
__global__ __launch_bounds__(256) void rmsnorm_k(const u16* __restrict__ in, int in_stride,
                                                 int L, const float* __restrict__ w,
                                                 u16* __restrict__ out, int out_stride) {
  int row = blockIdx.x;
  const u16* x = in + (size_t)row * in_stride;
  float ss = 0.f;
  for (int i = threadIdx.x * 8; i < L; i += 2048) {
    uint4 v = *(const uint4*)&x[i];
    const u16* p = (const u16*)&v;
#pragma unroll
    for (int e = 0; e < 8; ++e) { float f = bf2f(p[e]); ss += f * f; }
  }
#pragma unroll
  for (int m = 32; m >= 1; m >>= 1) ss += __shfl_xor(ss, m);
  __shared__ float red[4];
  if ((threadIdx.x & 63) == 0) red[threadIdx.x >> 6] = ss;
  __syncthreads();
  ss = red[0] + red[1] + red[2] + red[3];
  float inv = rsqrtf(ss / (float)L + 1e-6f);
  u16* o = out + (size_t)row * out_stride;
  for (int i = threadIdx.x * 8; i < L; i += 2048) {
    uint4 v = *(const uint4*)&x[i];
    const u16* p = (const u16*)&v;
    u16 r8[8];
#pragma unroll
    for (int e = 0; e < 8; ++e) r8[e] = f2bf(bf2f(p[e]) * inv * w[i + e]);
    *(uint4*)&o[i] = *(const uint4*)&r8[0];
  }
}

// ---------------- GEMM: A(MxK) bf16 row-major, Bt(NxK) bf16, C(MxN) ----------------
// 128x128 tile, BK=32, 4 waves (2x2), 64x64 per wave. 3-buffer depth-2 prefetch
// with counted vmcnt (T3+T4) + rule-#21 source-side swizzle (verified r8).
// EPI: 0 = f32 row-major, 1 = bf16 row-major, 3 = bf16 * softmax scale
template <int EPI>
__global__ __launch_bounds__(256) void gemm_bt(const u16* __restrict__ A,
                                               const u16* __restrict__ Bt,
                                               void* __restrict__ Cout,
                                               int M, int N, int K) {
  __shared__ u16 As[3][128 * 32];
  __shared__ u16 Bs[3][128 * 32];
  const int nbx = N >> 7;
  const int bx = blockIdx.x % nbx, by = blockIdx.x / nbx;
  const int m0 = by << 7, n0 = bx << 7;
  const int tid = threadIdx.x, w = tid >> 6, lane = tid & 63;
  const int wr = w >> 1, wc = w & 1;
  const int llo = lane & 15, lhi = lane >> 4;
  f32x4 acc[4][4] = {};

  const int c0 = tid, c1 = tid + 256;
  const int ar0 = c0 >> 2, s0_ = c0 & 3;
  const int ar1 = c1 >> 2, s1_ = c1 & 3;
  const u16* Asrc0 = A + (size_t)(m0 + ar0) * K + (s0_ ^ ((ar0 >> 1) & 3)) * 8;
  const u16* Asrc1 = A + (size_t)(m0 + ar1) * K + (s1_ ^ ((ar1 >> 1) & 3)) * 8;
  const u16* Bsrc0 = Bt + (size_t)(n0 + ar0) * K + (s0_ ^ ((ar0 >> 1) & 3)) * 8;
  const u16* Bsrc1 = Bt + (size_t)(n0 + ar1) * K + (s1_ ^ ((ar1 >> 1) & 3)) * 8;

  int aoff[4], boff[4];
#pragma unroll
  for (int i = 0; i < 4; ++i) {
    int rowa = wr * 64 + i * 16 + llo;
    aoff[i] = (rowa * 4 + (lhi ^ ((rowa >> 1) & 3))) * 8;
    int rowb = wc * 64 + i * 16 + llo;
    boff[i] = (rowb * 4 + (lhi ^ ((rowb >> 1) & 3))) * 8;
  }

#define STAGE_KT(kt, buf)                                   \
  do {                                                      \
    int k0_ = (kt) << 5;                                    \
    load_lds16(Asrc0 + k0_, &As[(buf)][c0 * 8]);            \
    load_lds16(Asrc1 + k0_, &As[(buf)][c1 * 8]);            \
    load_lds16(Bsrc0 + k0_, &Bs[(buf)][c0 * 8]);            \
    load_lds16(Bsrc1 + k0_, &Bs[(buf)][c1 * 8]);            \
  } while (0)

  const int NT = K >> 5;
  STAGE_KT(0, 0);
  STAGE_KT(1, 1);
  asm volatile("s_waitcnt vmcnt(4)" ::: "memory");
  __builtin_amdgcn_s_barrier();

  int cur = 0, nxt = 2;
  for (int kt = 0; kt < NT; ++kt) {
    if (kt + 2 < NT) STAGE_KT(kt + 2, nxt);
    short8 af[4], bfr[4];
#pragma unroll
    for (int i = 0; i < 4; ++i) af[i] = *(const short8*)&As[cur][aoff[i]];
#pragma unroll
    for (int j = 0; j < 4; ++j) bfr[j] = *(const short8*)&Bs[cur][boff[j]];
    __builtin_amdgcn_s_setprio(1);
#pragma unroll
    for (int i = 0; i < 4; ++i)
#pragma unroll
      for (int j = 0; j < 4; ++j)
        acc[i][j] = __builtin_amdgcn_mfma_f32_16x16x32_bf16(af[i], bfr[j], acc[i][j], 0, 0, 0);
    __builtin_amdgcn_s_setprio(0);
    if (kt + 2 < NT) asm volatile("s_waitcnt vmcnt(4)" ::: "memory");
    else             asm volatile("s_waitcnt vmcnt(0)" ::: "memory");
    __builtin_amdgcn_s_barrier();
    cur = (cur == 2) ? 0 : cur + 1;
    nxt = (nxt == 2) ? 0 : nxt + 1;
  }
#undef STAGE_KT

  if constexpr (EPI == 0) {
    float* C = (float*)Cout;
#pragma unroll
    for (int i = 0; i < 4; ++i)
#pragma unroll
      for (int j = 0; j < 4; ++j)
#pragma unroll
        for (int r = 0; r < 4; ++r)
          C[(size_t)(m0 + wr * 64 + i * 16 + lhi * 4 + r) * N + (n0 + wc * 64 + j * 16 + llo)] =
              acc[i][j][r];
  } else {
    const float scale = (EPI == 3) ? 0.10412163f : 1.0f;  // log2(e)/sqrt(192)
    u16* C = (u16*)Cout;
#pragma unroll
    for (int i = 0; i < 4; ++i)
#pragma unroll
      for (int j = 0; j < 4; ++j)
#pragma unroll
        for (int r = 0; r < 4; ++r)
          C[(size_t)(m0 + wr * 64 + i * 16 + lhi * 4 + r) * N + (n0 + wc * 64 + j * 16 + llo)] =
              f2bf(acc[i][j][r] * scale);
  }
}

// ---------------- V repack: kv cols 128..255 per head -> Vt (B,H,128,T) ----------------
__global__ __launch_bounds__(256) void pack_vt_k(const u16* __restrict__ kv, u16* __restrict__ Vt) {
  __shared__ u16 tile[64][136];
  const int nt = T_ / 64;  // 32
  int t0 = (blockIdx.x % nt) * 64;
  int bh = blockIdx.x / nt;
  int b = bh >> 4, h = bh & 15;
  int row = threadIdx.x >> 4;     // 0..15
  int ck = threadIdx.x & 15;      // 16 chunks of 8 = 128 dims
#pragma unroll
  for (int i = 0; i < 64; i += 16) {
    uint4 v = *(const uint4*)&kv[((size_t)(b * T_) + t0 + row + i) * 4096 + h * 256 + 128 + ck * 8];
    *(uint4*)&tile[row + i][ck * 8] = v;
  }
  __syncthreads();
  int d = threadIdx.x >> 1;
  int th = (threadIdx.x & 1) * 32;
  u16 tmp[32];
#pragma unroll
  for (int e = 0; e < 32; ++e) tmp[e] = tile[th + e][d];
#pragma unroll
  for (int e = 0; e < 32; e += 8)
    *(uint4*)&Vt[((size_t)bh * 128 + d) * T_ + t0 + th + e] = *(const uint4*)&tmp[e];
}

// ---------------- causal flash attention: 128-row q-tiles, 32 rows/wave ----------------
// vs r6 (verified 127us): each wave now owns 32 q-rows (two 16-row frags), block
// covers 128 q-rows -> staged bytes/barriers per q-row HALVED. Grid = 512 blocks
// (32 bh x 16 q-tiles): idx<256 are long tiles (qt=15-(idx>>5)), idx>=256 short
// (qt=idx>>5), same (idx>>5) pairs share bh and sum to uniform 34 k-tiles and
// co-reside on one CU (XCD L2 reuse -> FETCH should halve). Staging, swizzles,
// counted vmcnt, exp2 softmax, defer-max, deferred l-reduce identical to r6.
// LDS 48K(K dbuf)+16K(V)+16K(P) = 80 KB -> 2 blocks/CU. Plain launch_bounds
// (no min-wave hint: r2/r7 showed hints force scratch spills).
__global__ __launch_bounds__(256) void attn_k(const u16* __restrict__ q,
                                              const u16* __restrict__ kv,
                                              const u16* __restrict__ kvraw,
                                              const u16* __restrict__ Vt,
                                              u16* __restrict__ att) {
  constexpr int KLD = 192, VLD = 64, PLD = 64;
  __shared__ u16 Ks[2][64 * KLD];   // 48 KB
  __shared__ u16 Vs[128 * VLD];     // 16 KB
  __shared__ u16 Ps[128 * PLD];     // 16 KB
  const int idx = (int)blockIdx.x;
  int bh, qt;
  if (idx < 256) { bh = idx & 31; qt = 15 - (idx >> 5); }   // long tiles first
  else           { bh = idx & 31; qt = (idx - 256) >> 5; }  // paired shorts
  const int b = bh >> 4, h = bh & 15;
  const int bT = b * T_;
  const int q0 = qt * 128;
  const int tid = threadIdx.x, w = tid >> 6, lane = tid & 63;
  const int llo = lane & 15, lhi = lane >> 4;
  const int rbase = q0 + w * 32;   // wave's first q-row (32 rows/wave)
  const u16* Vb = Vt + (size_t)bh * DV_ * T_;

  // per-thread K staging sources, swizzle pre-folded into source (rule #21)
  const u16* kbase[6]; int kstr[6];
#pragma unroll
  for (int ii = 0; ii < 6; ++ii) {
    int c = ii * 256 + tid;            // 1536 chunks = 64 rows x 24 chunks
    int rr = c / 24, chk = c - rr * 24;
    int sc = chk ^ (rr & 7);           // source chunk for linear LDS slot
    if (sc < 16) { kbase[ii] = kv + (size_t)(bT + rr) * 4096 + h * 256 + sc * 8; kstr[ii] = 4096; }
    else { kbase[ii] = kvraw + (size_t)(bT + rr) * AW_ + 2048 + h * 64 + (sc - 16) * 8; kstr[ii] = AW_; }
  }
  int voff[4];
#pragma unroll
  for (int ii = 0; ii < 4; ++ii) {
    int c = ii * 256 + tid;            // 1024 chunks = 128 d-rows x 8 chunks
    int rr = c >> 3, chk = c & 7;
    voff[ii] = rr * T_ + (chk ^ (rr & 7)) * 8;
  }

  // Q frags: two 16-row blocks per wave
  short8 qf[2][6];
#pragma unroll
  for (int i = 0; i < 2; ++i)
#pragma unroll
    for (int kk = 0; kk < 6; ++kk)
      qf[i][kk] = *(const short8*)&q[(size_t)(bT + rbase + i * 16 + llo) * AW_ + h * DQK_ + kk * 32 + lhi * 8];
  f32x4 oacc[2][8] = {};
  float m_r[2][4], l_r[2][4];
#pragma unroll
  for (int i = 0; i < 2; ++i)
#pragma unroll
    for (int r = 0; r < 4; ++r) { m_r[i][r] = -1e30f; l_r[i][r] = 0.f; }

  // prologue: stage K[0]
#pragma unroll
  for (int ii = 0; ii < 6; ++ii)
    load_lds16(kbase[ii], &Ks[0][(ii * 256 + tid) * 8]);
  asm volatile("s_waitcnt vmcnt(0)" ::: "memory");
  __builtin_amdgcn_s_barrier();
  __builtin_amdgcn_sched_barrier(0);

  const int nkt = 2 * qt + 2;
  int cur = 0;
  for (int kt = 0; kt < nkt; ++kt) {
    const int k0 = kt * 64;
    const bool hasNext = (kt + 1 < nkt);
    // issue V[kt] -> Vs
#pragma unroll
    for (int ii = 0; ii < 4; ++ii)
      load_lds16(Vb + k0 + voff[ii], &Vs[(ii * 256 + tid) * 8]);
    // issue K[kt+1] -> other buffer
    if (hasNext) {
      u16* kd = Ks[cur ^ 1];
#pragma unroll
      for (int ii = 0; ii < 6; ++ii)
        load_lds16(kbase[ii] + (size_t)(k0 + 64) * kstr[ii], &kd[(ii * 256 + tid) * 8]);
    }
    // S = Q K^T from Ks[cur]
    const u16* kbuf = Ks[cur];
    f32x4 s[2][4] = {};
    __builtin_amdgcn_s_setprio(1);
#pragma unroll
    for (int kk = 0; kk < 6; ++kk) {
      const int col = kk * 32 + lhi * 8;
      short8 kf[4];
#pragma unroll
      for (int j = 0; j < 4; ++j) {
        const int row = j * 16 + llo;
        kf[j] = *(const short8*)&kbuf[row * KLD + (col ^ ((row & 7) << 3))];
      }
#pragma unroll
      for (int i = 0; i < 2; ++i)
#pragma unroll
        for (int j = 0; j < 4; ++j)
          s[i][j] = __builtin_amdgcn_mfma_f32_16x16x32_bf16(qf[i][kk], kf[j], s[i][j], 0, 0, 0);
    }
    __builtin_amdgcn_s_setprio(0);
    // online softmax (exp2 domain; Q pre-scaled by log2e/sqrt(192))
    const bool needMask = (k0 + 63 > rbase);
#pragma unroll
    for (int i = 0; i < 2; ++i)
#pragma unroll
      for (int r = 0; r < 4; ++r) {
        const int qrow = rbase + i * 16 + lhi * 4 + r;
        float sv[4];
#pragma unroll
        for (int j = 0; j < 4; ++j) {
          float x = s[i][j][r];
          if (needMask) { int kcol = k0 + j * 16 + llo; x = (kcol <= qrow) ? x : -1e30f; }
          sv[j] = x;
        }
        float mx = fmaxf(fmaxf(sv[0], sv[1]), fmaxf(sv[2], sv[3]));
#pragma unroll
        for (int mk = 1; mk < 16; mk <<= 1) mx = fmaxf(mx, __shfl_xor(mx, mk));
        if (!__all(mx - m_r[i][r] <= 8.f)) {   // defer-max (T13)
          float mnew = fmaxf(m_r[i][r], mx);
          float alpha = exp2f(m_r[i][r] - mnew);
          m_r[i][r] = mnew;
          l_r[i][r] *= alpha;
#pragma unroll
          for (int jo = 0; jo < 8; ++jo) oacc[i][jo][r] *= alpha;
        }
        float rs = 0.f;
        const int prow = w * 32 + i * 16 + lhi * 4 + r;
#pragma unroll
        for (int j = 0; j < 4; ++j) {
          float p = exp2f(sv[j] - m_r[i][r]);
          rs += p;
          int pcol = j * 16 + llo;
          Ps[prow * PLD + (pcol ^ ((prow & 7) << 3))] = f2bf(p);
        }
        l_r[i][r] += rs;   // per-lane partial; cross-lane reduce in epilogue
      }
    // V staged? (counted: leave the 6 K loads in flight)
    if (hasNext) asm volatile("s_waitcnt vmcnt(6)" ::: "memory");
    else         asm volatile("s_waitcnt vmcnt(0)" ::: "memory");
    __builtin_amdgcn_s_barrier();
    __builtin_amdgcn_sched_barrier(0);
    // PV (wave-local P rows; same-wave LDS RAW ordered by lgkmcnt)
    __builtin_amdgcn_s_setprio(1);
#pragma unroll
    for (int kk2 = 0; kk2 < 2; ++kk2) {
      const int pcol = kk2 * 32 + lhi * 8;
      short8 pf[2];
#pragma unroll
      for (int i = 0; i < 2; ++i) {
        const int prow = w * 32 + i * 16 + llo;
        pf[i] = *(const short8*)&Ps[prow * PLD + (pcol ^ ((prow & 7) << 3))];
      }
#pragma unroll
      for (int jo = 0; jo < 8; ++jo) {
        const int vrow = jo * 16 + llo;
        short8 vf = *(const short8*)&Vs[vrow * VLD + (pcol ^ ((vrow & 7) << 3))];
#pragma unroll
        for (int i = 0; i < 2; ++i)
          oacc[i][jo] = __builtin_amdgcn_mfma_f32_16x16x32_bf16(pf[i], vf, oacc[i][jo], 0, 0, 0);
      }
    }
    __builtin_amdgcn_s_setprio(0);
    // end of tile: K[t+1] landed; all waves done with Vs & Ks[cur]
    asm volatile("s_waitcnt vmcnt(0)" ::: "memory");
    __builtin_amdgcn_s_barrier();
    __builtin_amdgcn_sched_barrier(0);
    cur ^= 1;
  }
  // epilogue: reduce l partials across 16-lane group, store
#pragma unroll
  for (int i = 0; i < 2; ++i)
#pragma unroll
    for (int r = 0; r < 4; ++r) {
      float lr = l_r[i][r];
#pragma unroll
      for (int mk = 1; mk < 16; mk <<= 1) lr += __shfl_xor(lr, mk);
      const int qrow = rbase + i * 16 + lhi * 4 + r;
      const float linv = 1.f / lr;
#pragma unroll
      for (int jo = 0; jo < 8; ++jo)
        att[((size_t)bT + qrow) * (H_ * DV_) + h * DV_ + jo * 16 + llo] =
            f2bf(oacc[i][jo][r] * linv);
    }
}

// ---------------- launch ----------------
extern "C" void kernel_launch(void* const* d_in, const int* in_sizes, int n_in,
                              void* d_out, int out_size, void* d_ws, size_t ws_size,
                              hipStream_t stream) {
  const float* hs      = (const float*)d_in[0];
  const float* q_a_w   = (const float*)d_in[1];
  const float* q_a_ln  = (const float*)d_in[2];
  const float* q_b_w   = (const float*)d_in[3];
  const float* kv_a_w  = (const float*)d_in[4];
  const float* kv_a_ln = (const float*)d_in[5];
  const float* kv_b_w  = (const float*)d_in[6];
  const float* o_w     = (const float*)d_in[7];
  float* out = (float*)d_out;
  char* ws = (char*)d_ws;

  u16* hid  = (u16*)(ws + 0);          // 16.78 MB  (B*T, 2048) bf16
  u16* wt   = (u16*)(ws + 16777216);   // 12.58 MB  transposed weight (reused)
  u16* qa   = (u16*)(ws + 29360128);   // 25.17 MB  fused a-out: [q_a 1536 | kv_raw 1536]
  u16* qan  = (u16*)(ws + 54525952);   // 12.58 MB  q_a normed / later kv_latent
  u16* qout = (u16*)(ws + 67108864);   // 25.17 MB  q (B*T, 16*192), pre-scaled
  u16* att  = (u16*)(ws + 92274688);   // 16.78 MB  attn out (B*T, 2048)
  u16* kv   = (u16*)(ws + 109051904);  // 33.55 MB  kv_b out (k_nope|v per head)
  u16* Vt   = (u16*)(ws + 142606336);  // 16.78 MB  (B,H,128,T)

  cast_f32_bf16<<<4096, 256, 0, stream>>>(hs, hid);

  // fused a-proj: [q_a | kv_raw] = hid @ [q_a_w | kv_a_w]
  transpose_cast_k<<<dim3(1536 / 32, 2048 / 32), 256, 0, stream>>>(q_a_w, wt, 2048, 1536);
  transpose_cast_k<<<dim3(1536 / 32, 2048 / 32), 256, 0, stream>>>(kv_a_w, wt + (size_t)1536 * 2048, 2048, 1536);
  gemm_bt<1><<<(3072 / 128) * (4096 / 128), 256, 0, stream>>>(hid, wt, qa, 4096, 3072, 2048);

  // rmsnorm q_a -> qan
  rmsnorm_k<<<4096, 256, 0, stream>>>(qa, AW_, 1536, q_a_ln, qan, 1536);

  // q = qan @ q_b_w  (bf16, pre-scaled by log2e/sqrt(192))
  transpose_cast_k<<<dim3(3072 / 32, 1536 / 32), 256, 0, stream>>>(q_b_w, wt, 1536, 3072);
  gemm_bt<3><<<(3072 / 128) * (4096 / 128), 256, 0, stream>>>(qan, wt, qout, 4096, 3072, 1536);

  // rmsnorm kv latent (kv_raw = qa cols 1536..3071) -> qan (stride 512)
  rmsnorm_k<<<4096, 256, 0, stream>>>(qa + 1536, AW_, 512, kv_a_ln, qan, 512);

  // kv = kv_latent @ kv_b_w
  transpose_cast_k<<<dim3(4096 / 32, 512 / 32), 256, 0, stream>>>(kv_b_w, wt, 512, 4096);
  gemm_bt<1><<<(4096 / 128) * (4096 / 128), 256, 0, stream>>>(qan, wt, kv, 4096, 4096, 512);

  // V repack only (K staged in-place by attn from kv + qa)
  pack_vt_k<<<1024, 256, 0, stream>>>(kv, Vt);

  // attention -> att   (512 blocks: 128-row q-tiles, paired long/short on CUs)
  attn_k<<<512, 256, 0, stream>>>(qout, kv, qa, Vt, att);

  // out = att @ o_w
  transpose_cast_k<<<dim3(2048 / 32, 2048 / 32), 256, 0, stream>>>(o_w, wt, 2048, 2048);
  gemm_bt<0><<<(2048 / 128) * (4096 / 128), 256, 0, stream>>>(att, wt, out, 4096, 2048, 2048);
}

// Round 10
// 390.482 us; speedup vs baseline: 1.0935x; 1.0935x over previous
//
#include <hip/hip_runtime.h>
#include <cstdint>
#include <cstddef>

typedef unsigned short u16;
typedef short short8 __attribute__((ext_vector_type(8)));
typedef float f32x4 __attribute__((ext_vector_type(4)));

#define B_   2
#define T_   2048
#define H_   16
#define HID_ 2048
#define DQK_ 192
#define DV_  128
#define AW_  3072   // fused a-proj output width (q_a 1536 | kv_raw 1536)

__device__ __forceinline__ float bf2f(u16 u) {
  unsigned int v = ((unsigned int)u) << 16;
  return __builtin_bit_cast(float, v);
}
__device__ __forceinline__ u16 f2bf(float f) {
  unsigned int u = __builtin_bit_cast(unsigned int, f);
  u += 0x7fff + ((u >> 16) & 1);   // round-to-nearest-even
  return (u16)(u >> 16);
}
__device__ __forceinline__ void load_lds16(const void* g, void* l) {
  __builtin_amdgcn_global_load_lds((const __attribute__((address_space(1))) void*)g,
                                   (__attribute__((address_space(3))) void*)l, 16, 0, 0);
}

// ---------------- cast f32 -> bf16 (8 elems/thread) ----------------
__global__ __launch_bounds__(256) void cast_f32_bf16(const float* __restrict__ x,
                                                     u16* __restrict__ y) {
  size_t i = ((size_t)blockIdx.x * 256 + threadIdx.x) * 8;
  float4 a = *(const float4*)&x[i];
  float4 b = *(const float4*)&x[i + 4];
  u16 r[8];
  r[0] = f2bf(a.x); r[1] = f2bf(a.y); r[2] = f2bf(a.z); r[3] = f2bf(a.w);
  r[4] = f2bf(b.x); r[5] = f2bf(b.y); r[6] = f2bf(b.z); r[7] = f2bf(b.w);
  *(uint4*)&y[i] = *(const uint4*)&r[0];
}

// ---------------- W (K x N) f32  ->  Wt (N x K) bf16 ----------------
__global__ __launch_bounds__(256) void transpose_cast_k(const float* __restrict__ W,
                                                        u16* __restrict__ Wt,
                                                        int K, int N) {
  __shared__ u16 tile[32][33];
  int n0 = blockIdx.x * 32, k0 = blockIdx.y * 32;
  int tx = threadIdx.x & 31, ty = threadIdx.x >> 5;
#pragma unroll
  for (int i = 0; i < 32; i += 8)
    tile[ty + i][tx] = f2bf(W[(size_t)(k0 + ty + i) * N + n0 + tx]);
  __syncthreads();
#pragma unroll
  for (int i = 0; i < 32; i += 8)
    Wt[(size_t)(n0 + ty + i) * K + k0 + tx] = tile[tx][ty + i];
}

// ---------------- RMSNorm over rows (bf16 in/out, f32 weight) ----------------
__global__ __launch_bounds__(256) void rmsnorm_k(const u16* __restrict__ in, int in_stride,
                                                 int L, const float* __restrict__ w,
                                                 u16* __restrict__ out, int out_stride) {
  int row = blockIdx.x;
  const u16* x = in + (size_t)row * in_stride;
  float ss = 0.f;
  for (int i = threadIdx.x * 8; i < L; i += 2048) {
    uint4 v = *(const uint4*)&x[i];
    const u16* p = (const u16*)&v;
#pragma unroll
    for (int e = 0; e < 8; ++e) { float f = bf2f(p[e]); ss += f * f; }
  }
#pragma unroll
  for (int m = 32; m >= 1; m >>= 1) ss += __shfl_xor(ss, m);
  __shared__ float red[4];
  if ((threadIdx.x & 63) == 0) red[threadIdx.x >> 6] = ss;
  __syncthreads();
  ss = red[0] + red[1] + red[2] + red[3];
  float inv = rsqrtf(ss / (float)L + 1e-6f);
  u16* o = out + (size_t)row * out_stride;
  for (int i = threadIdx.x * 8; i < L; i += 2048) {
    uint4 v = *(const uint4*)&x[i];
    const u16* p = (const u16*)&v;
    u16 r8[8];
#pragma unroll
    for (int e = 0; e < 8; ++e) r8[e] = f2bf(bf2f(p[e]) * inv * w[i + e]);
    *(uint4*)&o[i] = *(const uint4*)&r8[0];
  }
}

// ---------------- GEMM: A(MxK) bf16 row-major, Bt(NxK) bf16, C(MxN) ----------------
// 256x128 tile, BK=32, 4 waves, wave tile 128x64 (8x4 16x16 frags): LDS reads per
// MFMA 0.5 -> 0.375 and staged bytes/MAC x0.75 vs r8's 128x128 (r8 GEMM is LDS-BW
// bound, m98 MfmaUtil 37%). Pipeline identical to verified r8: 3-buffer depth-2
// prefetch, counted vmcnt (stage t+2 = 6 loads; boundary vmcnt(6) -> t+1 landed,
// t+2 in flight), rule-#21 source-side XOR swizzle (slot ^ (row>>1)&3).
// LDS 3x(16+8)KB = 72KB -> 2 blocks/CU. acc 128 + af 64 + addr ~ 230 VGPR.
// EPI: 0 = f32 row-major, 1 = bf16 row-major, 3 = bf16 * softmax scale
template <int EPI>
__global__ __launch_bounds__(256, 2) void gemm_bt(const u16* __restrict__ A,
                                                  const u16* __restrict__ Bt,
                                                  void* __restrict__ Cout,
                                                  int M, int N, int K) {
  __shared__ u16 As[3][256 * 32];   // 48 KB
  __shared__ u16 Bs[3][128 * 32];   // 24 KB
  const int nbx = N >> 7;
  const int bx = blockIdx.x % nbx, by = blockIdx.x / nbx;
  const int m0 = by << 8, n0 = bx << 7;
  const int tid = threadIdx.x, w = tid >> 6, lane = tid & 63;
  const int wr = w >> 1, wc = w & 1;   // wr: 128-row half, wc: 64-col half
  const int llo = lane & 15, lhi = lane >> 4;
  f32x4 acc[8][4] = {};

  // A: 1024 chunks (256 rows x 4 slots of 16B), 4/thread; B: 512 chunks, 2/thread.
  // source col pre-swizzled (rule #21): LDS slot s of row r holds col (s ^ ((r>>1)&3)).
  const u16* Asrc0; const u16* Asrc1; const u16* Asrc2; const u16* Asrc3;
  {
    int c, r, s;
    c = tid;       r = c >> 2; s = c & 3; Asrc0 = A + (size_t)(m0 + r) * K + (s ^ ((r >> 1) & 3)) * 8;
    c = tid + 256; r = c >> 2; s = c & 3; Asrc1 = A + (size_t)(m0 + r) * K + (s ^ ((r >> 1) & 3)) * 8;
    c = tid + 512; r = c >> 2; s = c & 3; Asrc2 = A + (size_t)(m0 + r) * K + (s ^ ((r >> 1) & 3)) * 8;
    c = tid + 768; r = c >> 2; s = c & 3; Asrc3 = A + (size_t)(m0 + r) * K + (s ^ ((r >> 1) & 3)) * 8;
  }
  const u16* Bsrc0; const u16* Bsrc1;
  {
    int c, r, s;
    c = tid;       r = c >> 2; s = c & 3; Bsrc0 = Bt + (size_t)(n0 + r) * K + (s ^ ((r >> 1) & 3)) * 8;
    c = tid + 256; r = c >> 2; s = c & 3; Bsrc1 = Bt + (size_t)(n0 + r) * K + (s ^ ((r >> 1) & 3)) * 8;
  }

  int aoff[8], boff[4];
#pragma unroll
  for (int i = 0; i < 8; ++i) {
    int row = wr * 128 + i * 16 + llo;
    aoff[i] = (row * 4 + (lhi ^ ((row >> 1) & 3))) * 8;
  }
#pragma unroll
  for (int j = 0; j < 4; ++j) {
    int row = wc * 64 + j * 16 + llo;
    boff[j] = (row * 4 + (lhi ^ ((row >> 1) & 3))) * 8;
  }

#define STAGE_KT(kt, buf)                                   \
  do {                                                      \
    int k0_ = (kt) << 5;                                    \
    load_lds16(Asrc0 + k0_, &As[(buf)][(tid      ) * 8]);   \
    load_lds16(Asrc1 + k0_, &As[(buf)][(tid + 256) * 8]);   \
    load_lds16(Asrc2 + k0_, &As[(buf)][(tid + 512) * 8]);   \
    load_lds16(Asrc3 + k0_, &As[(buf)][(tid + 768) * 8]);   \
    load_lds16(Bsrc0 + k0_, &Bs[(buf)][(tid      ) * 8]);   \
    load_lds16(Bsrc1 + k0_, &Bs[(buf)][(tid + 256) * 8]);   \
  } while (0)

  const int NT = K >> 5;
  STAGE_KT(0, 0);
  STAGE_KT(1, 1);
  asm volatile("s_waitcnt vmcnt(6)" ::: "memory");   // tile 0 landed; tile 1 in flight
  __builtin_amdgcn_s_barrier();

  int cur = 0, nxt = 2;
  for (int kt = 0; kt < NT; ++kt) {
    if (kt + 2 < NT) STAGE_KT(kt + 2, nxt);
    short8 af[8];
#pragma unroll
    for (int i = 0; i < 8; ++i) af[i] = *(const short8*)&As[cur][aoff[i]];
    __builtin_amdgcn_s_setprio(1);
#pragma unroll
    for (int j = 0; j < 4; ++j) {
      short8 bf = *(const short8*)&Bs[cur][boff[j]];
#pragma unroll
      for (int i = 0; i < 8; ++i)
        acc[i][j] = __builtin_amdgcn_mfma_f32_16x16x32_bf16(af[i], bf, acc[i][j], 0, 0, 0);
    }
    __builtin_amdgcn_s_setprio(0);
    if (kt + 2 < NT) asm volatile("s_waitcnt vmcnt(6)" ::: "memory");  // t+1 landed
    else             asm volatile("s_waitcnt vmcnt(0)" ::: "memory");  // tail drain
    __builtin_amdgcn_s_barrier();
    cur = (cur == 2) ? 0 : cur + 1;
    nxt = (nxt == 2) ? 0 : nxt + 1;
  }
#undef STAGE_KT

  if constexpr (EPI == 0) {
    float* C = (float*)Cout;
#pragma unroll
    for (int i = 0; i < 8; ++i)
#pragma unroll
      for (int j = 0; j < 4; ++j)
#pragma unroll
        for (int r = 0; r < 4; ++r)
          C[(size_t)(m0 + wr * 128 + i * 16 + lhi * 4 + r) * N + (n0 + wc * 64 + j * 16 + llo)] =
              acc[i][j][r];
  } else {
    const float scale = (EPI == 3) ? 0.10412163f : 1.0f;  // log2(e)/sqrt(192)
    u16* C = (u16*)Cout;
#pragma unroll
    for (int i = 0; i < 8; ++i)
#pragma unroll
      for (int j = 0; j < 4; ++j)
#pragma unroll
        for (int r = 0; r < 4; ++r)
          C[(size_t)(m0 + wr * 128 + i * 16 + lhi * 4 + r) * N + (n0 + wc * 64 + j * 16 + llo)] =
              f2bf(acc[i][j][r] * scale);
  }
}

// ---------------- V repack: kv cols 128..255 per head -> Vt (B,H,128,T) ----------------
__global__ __launch_bounds__(256) void pack_vt_k(const u16* __restrict__ kv, u16* __restrict__ Vt) {
  __shared__ u16 tile[64][136];
  const int nt = T_ / 64;  // 32
  int t0 = (blockIdx.x % nt) * 64;
  int bh = blockIdx.x / nt;
  int b = bh >> 4, h = bh & 15;
  int row = threadIdx.x >> 4;     // 0..15
  int ck = threadIdx.x & 15;      // 16 chunks of 8 = 128 dims
#pragma unroll
  for (int i = 0; i < 64; i += 16) {
    uint4 v = *(const uint4*)&kv[((size_t)(b * T_) + t0 + row + i) * 4096 + h * 256 + 128 + ck * 8];
    *(uint4*)&tile[row + i][ck * 8] = v;
  }
  __syncthreads();
  int d = threadIdx.x >> 1;
  int th = (threadIdx.x & 1) * 32;
  u16 tmp[32];
#pragma unroll
  for (int e = 0; e < 32; ++e) tmp[e] = tile[th + e][d];
#pragma unroll
  for (int e = 0; e < 32; e += 8)
    *(uint4*)&Vt[((size_t)bh * 128 + d) * T_ + t0 + th + e] = *(const uint4*)&tmp[e];
}

// ---------------- causal flash attention (round-6 verified + lazy row-max) ----------------
// grid = 32 bh x 16 pairs; block 256 (4 waves x 16 q-rows); k-tile 64.
// Each block runs TWO 64-row Q-tiles (qt=31-pr then qt=pr) -> 33 k-tiles/block.
// global_load_lds staging, K double-buffered, counted vmcnt; source-side XOR
// swizzle (rule #21); exp2 softmax w/ prefolded scale; deferred l-reduce.
// NEW: lazy row-max -- check __all(lane-local max - m <= 8) FIRST; the 4-step
// shfl row-max runs only in the rare rescale branch (removes 16 ds_swizzle per
// tile-wave in steady state). LDS 72KB -> 2 blocks/CU. 127us verified base.
__global__ __launch_bounds__(256, 2) void attn_k(const u16* __restrict__ q,
                                                 const u16* __restrict__ kv,
                                                 const u16* __restrict__ kvraw,
                                                 const u16* __restrict__ Vt,
                                                 u16* __restrict__ att) {
  constexpr int KLD = 192, VLD = 64, PLD = 64;
  __shared__ u16 Ks[2][64 * KLD];
  __shared__ u16 Vs[128 * VLD];
  __shared__ u16 Ps[64 * PLD];
  const int idx = (int)blockIdx.x;
  const int bh = idx >> 4, pr = idx & 15;
  const int b = bh >> 4, h = bh & 15;
  const int bT = b * T_;
  const int tid = threadIdx.x, w = tid >> 6, lane = tid & 63;
  const int llo = lane & 15, lhi = lane >> 4;
  const u16* Vb = Vt + (size_t)bh * DV_ * T_;

  // per-thread K staging sources, swizzle pre-folded into source (rule #21)
  const u16* kbase[6]; int kstr[6];
#pragma unroll
  for (int ii = 0; ii < 6; ++ii) {
    int c = ii * 256 + tid;            // 1536 chunks = 64 rows x 24 chunks
    int rr = c / 24, chk = c - rr * 24;
    int sc = chk ^ (rr & 7);           // source chunk for linear LDS slot
    if (sc < 16) { kbase[ii] = kv + (size_t)(bT + rr) * 4096 + h * 256 + sc * 8; kstr[ii] = 4096; }
    else { kbase[ii] = kvraw + (size_t)(bT + rr) * AW_ + 2048 + h * 64 + (sc - 16) * 8; kstr[ii] = AW_; }
  }
  int voff[4];
#pragma unroll
  for (int ii = 0; ii < 4; ++ii) {
    int c = ii * 256 + tid;            // 1024 chunks = 128 d-rows x 8 chunks
    int rr = c >> 3, chk = c & 7;
    voff[ii] = rr * T_ + (chk ^ (rr & 7)) * 8;
  }

#pragma unroll
  for (int pass = 0; pass < 2; ++pass) {
    const int qt = pass == 0 ? 31 - pr : pr;
    const int q0 = qt * 64;
    const int rbase = q0 + w * 16;
    short8 qf[6];
#pragma unroll
    for (int kk = 0; kk < 6; ++kk)
      qf[kk] = *(const short8*)&q[(size_t)(bT + rbase + llo) * AW_ + h * DQK_ + kk * 32 + lhi * 8];
    f32x4 oacc[8] = {};
    float m_r[4], l_r[4];
#pragma unroll
    for (int r = 0; r < 4; ++r) { m_r[r] = -1e30f; l_r[r] = 0.f; }

    // prologue: stage K[0] into Ks[0]
#pragma unroll
    for (int ii = 0; ii < 6; ++ii)
      load_lds16(kbase[ii], &Ks[0][(ii * 256 + tid) * 8]);
    asm volatile("s_waitcnt vmcnt(0)" ::: "memory");
    __builtin_amdgcn_s_barrier();
    __builtin_amdgcn_sched_barrier(0);

    const int nkt = qt + 1;
    int cur = 0;
    for (int kt = 0; kt < nkt; ++kt) {
      const int k0 = kt * 64;
      const bool hasNext = (kt + 1 < nkt);
      // issue V[kt] -> Vs
#pragma unroll
      for (int ii = 0; ii < 4; ++ii)
        load_lds16(Vb + k0 + voff[ii], &Vs[(ii * 256 + tid) * 8]);
      // issue K[kt+1] -> other buffer
      if (hasNext) {
        u16* kd = Ks[cur ^ 1];
#pragma unroll
        for (int ii = 0; ii < 6; ++ii)
          load_lds16(kbase[ii] + (size_t)(k0 + 64) * kstr[ii], &kd[(ii * 256 + tid) * 8]);
      }
      // S = Q K^T from Ks[cur]
      const u16* kbuf = Ks[cur];
      f32x4 s[4] = {};
      __builtin_amdgcn_s_setprio(1);
#pragma unroll
      for (int kk = 0; kk < 6; ++kk) {
        const int col = kk * 32 + lhi * 8;
        short8 kf[4];
#pragma unroll
        for (int j = 0; j < 4; ++j) {
          const int row = j * 16 + llo;
          kf[j] = *(const short8*)&kbuf[row * KLD + (col ^ ((row & 7) << 3))];
        }
#pragma unroll
        for (int j = 0; j < 4; ++j)
          s[j] = __builtin_amdgcn_mfma_f32_16x16x32_bf16(qf[kk], kf[j], s[j], 0, 0, 0);
      }
      __builtin_amdgcn_s_setprio(0);
      // online softmax (exp2 domain; Q pre-scaled by log2e/sqrt(192))
      const bool needMask = (k0 + 63 > rbase);
#pragma unroll
      for (int r = 0; r < 4; ++r) {
        const int qrow = rbase + lhi * 4 + r;
        float sv[4];
#pragma unroll
        for (int j = 0; j < 4; ++j) {
          float x = s[j][r];
          if (needMask) { int kcol = k0 + j * 16 + llo; x = (kcol <= qrow) ? x : -1e30f; }
          sv[j] = x;
        }
        // lazy row-max (defer-max T13): lane-local bound check first; the
        // cross-lane max + rescale only when some lane exceeds m+8.
        float mx4 = fmaxf(fmaxf(sv[0], sv[1]), fmaxf(sv[2], sv[3]));
        if (!__all(mx4 - m_r[r] <= 8.f)) {
          float mx = mx4;
#pragma unroll
          for (int mk = 1; mk < 16; mk <<= 1) mx = fmaxf(mx, __shfl_xor(mx, mk));
          float mnew = fmaxf(m_r[r], mx);
          float alpha = exp2f(m_r[r] - mnew);
          m_r[r] = mnew;
          l_r[r] *= alpha;
#pragma unroll
          for (int jo = 0; jo < 8; ++jo) oacc[jo][r] *= alpha;
        }
        float rs = 0.f;
        const int prow = w * 16 + lhi * 4 + r;
#pragma unroll
        for (int j = 0; j < 4; ++j) {
          float p = exp2f(sv[j] - m_r[r]);   // bounded by 2^8
          rs += p;
          int pcol = j * 16 + llo;
          Ps[prow * PLD + (pcol ^ ((prow & 7) << 3))] = f2bf(p);
        }
        l_r[r] += rs;   // per-lane partial; cross-lane reduce in epilogue
      }
      // V staged? (counted: leave the 6 K loads in flight)
      if (hasNext) asm volatile("s_waitcnt vmcnt(6)" ::: "memory");
      else         asm volatile("s_waitcnt vmcnt(0)" ::: "memory");
      __builtin_amdgcn_s_barrier();
      __builtin_amdgcn_sched_barrier(0);
      // PV (wave-local P rows; same-wave LDS RAW ordered by lgkmcnt)
      __builtin_amdgcn_s_setprio(1);
#pragma unroll
      for (int kk2 = 0; kk2 < 2; ++kk2) {
        const int prow = w * 16 + llo;
        const int pcol = kk2 * 32 + lhi * 8;
        short8 pf = *(const short8*)&Ps[prow * PLD + (pcol ^ ((prow & 7) << 3))];
#pragma unroll
        for (int jo = 0; jo < 8; ++jo) {
          const int vrow = jo * 16 + llo;
          short8 vf = *(const short8*)&Vs[vrow * VLD + (pcol ^ ((vrow & 7) << 3))];
          oacc[jo] = __builtin_amdgcn_mfma_f32_16x16x32_bf16(pf, vf, oacc[jo], 0, 0, 0);
        }
      }
      __builtin_amdgcn_s_setprio(0);
      // end of tile: K[t+1] landed; all waves done with Vs & Ks[cur]
      asm volatile("s_waitcnt vmcnt(0)" ::: "memory");
      __builtin_amdgcn_s_barrier();
      __builtin_amdgcn_sched_barrier(0);
      cur ^= 1;
    }
    // epilogue: reduce l partials across 16-lane group, store
#pragma unroll
    for (int r = 0; r < 4; ++r) {
      float lr = l_r[r];
#pragma unroll
      for (int mk = 1; mk < 16; mk <<= 1) lr += __shfl_xor(lr, mk);
      const int qrow = rbase + lhi * 4 + r;
      const float linv = 1.f / lr;
#pragma unroll
      for (int jo = 0; jo < 8; ++jo)
        att[((size_t)bT + qrow) * (H_ * DV_) + h * DV_ + jo * 16 + llo] =
            f2bf(oacc[jo][r] * linv);
    }
  }
}

// ---------------- launch ----------------
extern "C" void kernel_launch(void* const* d_in, const int* in_sizes, int n_in,
                              void* d_out, int out_size, void* d_ws, size_t ws_size,
                              hipStream_t stream) {
  const float* hs      = (const float*)d_in[0];
  const float* q_a_w   = (const float*)d_in[1];
  const float* q_a_ln  = (const float*)d_in[2];
  const float* q_b_w   = (const float*)d_in[3];
  const float* kv_a_w  = (const float*)d_in[4];
  const float* kv_a_ln = (const float*)d_in[5];
  const float* kv_b_w  = (const float*)d_in[6];
  const float* o_w     = (const float*)d_in[7];
  float* out = (float*)d_out;
  char* ws = (char*)d_ws;

  u16* hid  = (u16*)(ws + 0);          // 16.78 MB  (B*T, 2048) bf16
  u16* wt   = (u16*)(ws + 16777216);   // 12.58 MB  transposed weight (reused)
  u16* qa   = (u16*)(ws + 29360128);   // 25.17 MB  fused a-out: [q_a 1536 | kv_raw 1536]
  u16* qan  = (u16*)(ws + 54525952);   // 12.58 MB  q_a normed / later kv_latent
  u16* qout = (u16*)(ws + 67108864);   // 25.17 MB  q (B*T, 16*192), pre-scaled
  u16* att  = (u16*)(ws + 92274688);   // 16.78 MB  attn out (B*T, 2048)
  u16* kv   = (u16*)(ws + 109051904);  // 33.55 MB  kv_b out (k_nope|v per head)
  u16* Vt   = (u16*)(ws + 142606336);  // 16.78 MB  (B,H,128,T)

  cast_f32_bf16<<<4096, 256, 0, stream>>>(hs, hid);

  // fused a-proj: [q_a | kv_raw] = hid @ [q_a_w | kv_a_w]
  transpose_cast_k<<<dim3(1536 / 32, 2048 / 32), 256, 0, stream>>>(q_a_w, wt, 2048, 1536);
  transpose_cast_k<<<dim3(1536 / 32, 2048 / 32), 256, 0, stream>>>(kv_a_w, wt + (size_t)1536 * 2048, 2048, 1536);
  gemm_bt<1><<<(3072 / 128) * (4096 / 256), 256, 0, stream>>>(hid, wt, qa, 4096, 3072, 2048);

  // rmsnorm q_a -> qan
  rmsnorm_k<<<4096, 256, 0, stream>>>(qa, AW_, 1536, q_a_ln, qan, 1536);

  // q = qan @ q_b_w  (bf16, pre-scaled by log2e/sqrt(192))
  transpose_cast_k<<<dim3(3072 / 32, 1536 / 32), 256, 0, stream>>>(q_b_w, wt, 1536, 3072);
  gemm_bt<3><<<(3072 / 128) * (4096 / 256), 256, 0, stream>>>(qan, wt, qout, 4096, 3072, 1536);

  // rmsnorm kv latent (kv_raw = qa cols 1536..3071) -> qan (stride 512)
  rmsnorm_k<<<4096, 256, 0, stream>>>(qa + 1536, AW_, 512, kv_a_ln, qan, 512);

  // kv = kv_latent @ kv_b_w
  transpose_cast_k<<<dim3(4096 / 32, 512 / 32), 256, 0, stream>>>(kv_b_w, wt, 512, 4096);
  gemm_bt<1><<<(4096 / 128) * (4096 / 256), 256, 0, stream>>>(qan, wt, kv, 4096, 4096, 512);

  // V repack only (K staged in-place by attn from kv + qa)
  pack_vt_k<<<1024, 256, 0, stream>>>(kv, Vt);

  // attention -> att   (512 balanced blocks, round-6 verified kernel + lazy max)
  attn_k<<<512, 256, 0, stream>>>(qout, kv, qa, Vt, att);

  // out = att @ o_w
  transpose_cast_k<<<dim3(2048 / 32, 2048 / 32), 256, 0, stream>>>(o_w, wt, 2048, 2048);
  gemm_bt<0><<<(2048 / 128) * (4096 / 256), 256, 0, stream>>>(att, wt, out, 4096, 2048, 2048);
}

// Round 11
// 336.383 us; speedup vs baseline: 1.2693x; 1.1608x over previous
//
#include <hip/hip_runtime.h>
#include <cstdint>
#include <cstddef>

typedef unsigned short u16;
typedef short short8 __attribute__((ext_vector_type(8)));
typedef float f32x4 __attribute__((ext_vector_type(4)));

#define B_   2
#define T_   2048
#define H_   16
#define HID_ 2048
#define DQK_ 192
#define DV_  128
#define AW_  3072   // fused a-proj output width (q_a 1536 | kv_raw 1536)

__device__ __forceinline__ float bf2f(u16 u) {
  unsigned int v = ((unsigned int)u) << 16;
  return __builtin_bit_cast(float, v);
}
__device__ __forceinline__ u16 f2bf(float f) {
  unsigned int u = __builtin_bit_cast(unsigned int, f);
  u += 0x7fff + ((u >> 16) & 1);   // round-to-nearest-even
  return (u16)(u >> 16);
}
__device__ __forceinline__ void load_lds16(const void* g, void* l) {
  __builtin_amdgcn_global_load_lds((const __attribute__((address_space(1))) void*)g,
                                   (__attribute__((address_space(3))) void*)l, 16, 0, 0);
}

// ---------------- cast f32 -> bf16 (8 elems/thread) ----------------
__global__ __launch_bounds__(256) void cast_f32_bf16(const float* __restrict__ x,
                                                     u16* __restrict__ y) {
  size_t i = ((size_t)blockIdx.x * 256 + threadIdx.x) * 8;
  float4 a = *(const float4*)&x[i];
  float4 b = *(const float4*)&x[i + 4];
  u16 r[8];
  r[0] = f2bf(a.x); r[1] = f2bf(a.y); r[2] = f2bf(a.z); r[3] = f2bf(a.w);
  r[4] = f2bf(b.x); r[5] = f2bf(b.y); r[6] = f2bf(b.z); r[7] = f2bf(b.w);
  *(uint4*)&y[i] = *(const uint4*)&r[0];
}

// ---------------- W (K x N) f32  ->  Wt (N x K) bf16 ----------------
__global__ __launch_bounds__(256) void transpose_cast_k(const float* __restrict__ W,
                                                        u16* __restrict__ Wt,
                                                        int K, int N) {
  __shared__ u16 tile[32][33];
  int n0 = blockIdx.x * 32, k0 = blockIdx.y * 32;
  int tx = threadIdx.x & 31, ty = threadIdx.x >> 5;
#pragma unroll
  for (int i = 0; i < 32; i += 8)
    tile[ty + i][tx] = f2bf(W[(size_t)(k0 + ty + i) * N + n0 + tx]);
  __syncthreads();
#pragma unroll
  for (int i = 0; i < 32; i += 8)
    Wt[(size_t)(n0 + ty + i) * K + k0 + tx] = tile[tx][ty + i];
}

// ---------------- RMSNorm over rows (bf16 in/out, f32 weight) ----------------
__global__ __launch_bounds__(256) void rmsnorm_k(const u16* __restrict__ in, int in_stride,
                                                 int L, const float* __restrict__ w,
                                                 u16* __restrict__ out, int out_stride) {
  int row = blockIdx.x;
  const u16* x = in + (size_t)row * in_stride;
  float ss = 0.f;
  for (int i = threadIdx.x * 8; i < L; i += 2048) {
    uint4 v = *(const uint4*)&x[i];
    const u16* p = (const u16*)&v;
#pragma unroll
    for (int e = 0; e < 8; ++e) { float f = bf2f(p[e]); ss += f * f; }
  }
#pragma unroll
  for (int m = 32; m >= 1; m >>= 1) ss += __shfl_xor(ss, m);
  __shared__ float red[4];
  if ((threadIdx.x & 63) == 0) red[threadIdx.x >> 6] = ss;
  __syncthreads();
  ss = red[0] + red[1] + red[2] + red[3];
  float inv = rsqrtf(ss / (float)L + 1e-6f);
  u16* o = out + (size_t)row * out_stride;
  for (int i = threadIdx.x * 8; i < L; i += 2048) {
    uint4 v = *(const uint4*)&x[i];
    const u16* p = (const u16*)&v;
    u16 r8[8];
#pragma unroll
    for (int e = 0; e < 8; ++e) r8[e] = f2bf(bf2f(p[e]) * inv * w[i + e]);
    *(uint4*)&o[i] = *(const uint4*)&r8[0];
  }
}

// ---------------- GEMM: A(MxK) bf16 row-major, Bt(NxK) bf16, C(MxN) ----------------
// VERIFIED r8 version: 128x128 tile, BK=32, 4 waves (2x2), 64x64 per wave.
// 3-buffer depth-2 prefetch with counted vmcnt (T3+T4) + rule-#21 source-side
// swizzle. r9/r10 showed bigger wave tiles (32q-rows attn, 256x128 gemm) lose
// to this via VGPR->occupancy; do not scale the tile, change the structure.
// EPI: 0 = f32 row-major, 1 = bf16 row-major, 3 = bf16 * softmax scale
template <int EPI>
__global__ __launch_bounds__(256) void gemm_bt(const u16* __restrict__ A,
                                               const u16* __restrict__ Bt,
                                               void* __restrict__ Cout,
                                               int M, int N, int K) {
  __shared__ u16 As[3][128 * 32];
  __shared__ u16 Bs[3][128 * 32];
  const int nbx = N >> 7;
  const int bx = blockIdx.x % nbx, by = blockIdx.x / nbx;
  const int m0 = by << 7, n0 = bx << 7;
  const int tid = threadIdx.x, w = tid >> 6, lane = tid & 63;
  const int wr = w >> 1, wc = w & 1;
  const int llo = lane & 15, lhi = lane >> 4;
  f32x4 acc[4][4] = {};

  const int c0 = tid, c1 = tid + 256;
  const int ar0 = c0 >> 2, s0_ = c0 & 3;
  const int ar1 = c1 >> 2, s1_ = c1 & 3;
  const u16* Asrc0 = A + (size_t)(m0 + ar0) * K + (s0_ ^ ((ar0 >> 1) & 3)) * 8;
  const u16* Asrc1 = A + (size_t)(m0 + ar1) * K + (s1_ ^ ((ar1 >> 1) & 3)) * 8;
  const u16* Bsrc0 = Bt + (size_t)(n0 + ar0) * K + (s0_ ^ ((ar0 >> 1) & 3)) * 8;
  const u16* Bsrc1 = Bt + (size_t)(n0 + ar1) * K + (s1_ ^ ((ar1 >> 1) & 3)) * 8;

  int aoff[4], boff[4];
#pragma unroll
  for (int i = 0; i < 4; ++i) {
    int rowa = wr * 64 + i * 16 + llo;
    aoff[i] = (rowa * 4 + (lhi ^ ((rowa >> 1) & 3))) * 8;
    int rowb = wc * 64 + i * 16 + llo;
    boff[i] = (rowb * 4 + (lhi ^ ((rowb >> 1) & 3))) * 8;
  }

#define STAGE_KT(kt, buf)                                   \
  do {                                                      \
    int k0_ = (kt) << 5;                                    \
    load_lds16(Asrc0 + k0_, &As[(buf)][c0 * 8]);            \
    load_lds16(Asrc1 + k0_, &As[(buf)][c1 * 8]);            \
    load_lds16(Bsrc0 + k0_, &Bs[(buf)][c0 * 8]);            \
    load_lds16(Bsrc1 + k0_, &Bs[(buf)][c1 * 8]);            \
  } while (0)

  const int NT = K >> 5;
  STAGE_KT(0, 0);
  STAGE_KT(1, 1);
  asm volatile("s_waitcnt vmcnt(4)" ::: "memory");
  __builtin_amdgcn_s_barrier();

  int cur = 0, nxt = 2;
  for (int kt = 0; kt < NT; ++kt) {
    if (kt + 2 < NT) STAGE_KT(kt + 2, nxt);
    short8 af[4], bfr[4];
#pragma unroll
    for (int i = 0; i < 4; ++i) af[i] = *(const short8*)&As[cur][aoff[i]];
#pragma unroll
    for (int j = 0; j < 4; ++j) bfr[j] = *(const short8*)&Bs[cur][boff[j]];
    __builtin_amdgcn_s_setprio(1);
#pragma unroll
    for (int i = 0; i < 4; ++i)
#pragma unroll
      for (int j = 0; j < 4; ++j)
        acc[i][j] = __builtin_amdgcn_mfma_f32_16x16x32_bf16(af[i], bfr[j], acc[i][j], 0, 0, 0);
    __builtin_amdgcn_s_setprio(0);
    if (kt + 2 < NT) asm volatile("s_waitcnt vmcnt(4)" ::: "memory");
    else             asm volatile("s_waitcnt vmcnt(0)" ::: "memory");
    __builtin_amdgcn_s_barrier();
    cur = (cur == 2) ? 0 : cur + 1;
    nxt = (nxt == 2) ? 0 : nxt + 1;
  }
#undef STAGE_KT

  if constexpr (EPI == 0) {
    float* C = (float*)Cout;
#pragma unroll
    for (int i = 0; i < 4; ++i)
#pragma unroll
      for (int j = 0; j < 4; ++j)
#pragma unroll
        for (int r = 0; r < 4; ++r)
          C[(size_t)(m0 + wr * 64 + i * 16 + lhi * 4 + r) * N + (n0 + wc * 64 + j * 16 + llo)] =
              acc[i][j][r];
  } else {
    const float scale = (EPI == 3) ? 0.10412163f : 1.0f;  // log2(e)/sqrt(192)
    u16* C = (u16*)Cout;
#pragma unroll
    for (int i = 0; i < 4; ++i)
#pragma unroll
      for (int j = 0; j < 4; ++j)
#pragma unroll
        for (int r = 0; r < 4; ++r)
          C[(size_t)(m0 + wr * 64 + i * 16 + lhi * 4 + r) * N + (n0 + wc * 64 + j * 16 + llo)] =
              f2bf(acc[i][j][r] * scale);
  }
}

// ---------------- V repack: kv cols 128..255 per head -> Vt (B,H,128,T) ----------------
__global__ __launch_bounds__(256) void pack_vt_k(const u16* __restrict__ kv, u16* __restrict__ Vt) {
  __shared__ u16 tile[64][136];
  const int nt = T_ / 64;  // 32
  int t0 = (blockIdx.x % nt) * 64;
  int bh = blockIdx.x / nt;
  int b = bh >> 4, h = bh & 15;
  int row = threadIdx.x >> 4;     // 0..15
  int ck = threadIdx.x & 15;      // 16 chunks of 8 = 128 dims
#pragma unroll
  for (int i = 0; i < 64; i += 16) {
    uint4 v = *(const uint4*)&kv[((size_t)(b * T_) + t0 + row + i) * 4096 + h * 256 + 128 + ck * 8];
    *(uint4*)&tile[row + i][ck * 8] = v;
  }
  __syncthreads();
  int d = threadIdx.x >> 1;
  int th = (threadIdx.x & 1) * 32;
  u16 tmp[32];
#pragma unroll
  for (int e = 0; e < 32; ++e) tmp[e] = tile[th + e][d];
#pragma unroll
  for (int e = 0; e < 32; e += 8)
    *(uint4*)&Vt[((size_t)bh * 128 + d) * T_ + t0 + th + e] = *(const uint4*)&tmp[e];
}

// ---------------- causal flash attention (r10 verified + XCD-aware bh grouping) ----------------
// block 256 (4 waves x 16 q-rows); k-tile 64; TWO passes (qt=31-pr, qt=pr) = 33
// k-tiles/block. NEW: blockIdx decode xcd=p&7, j=p>>3; bh=xcd*4+(j&3); pr=j>>2.
// Round-robin dispatch puts idx%8 on XCD idx%8 -> each XCD serves exactly 4 bh
// (5.2MB K/V working set ~ its 4MB L2, vs 41MB thrash when bh scattered; r10
// FETCH was 246MB vs 84MB ideal). Staging/swizzle/softmax identical to r10:
// global_load_lds, K dbuf, counted vmcnt, source-side XOR (rule #21), exp2
// softmax, lazy row-max (T13), deferred l-reduce. LDS 72KB -> 2 blocks/CU.
__global__ __launch_bounds__(256, 2) void attn_k(const u16* __restrict__ q,
                                                 const u16* __restrict__ kv,
                                                 const u16* __restrict__ kvraw,
                                                 const u16* __restrict__ Vt,
                                                 u16* __restrict__ att) {
  constexpr int KLD = 192, VLD = 64, PLD = 64;
  __shared__ u16 Ks[2][64 * KLD];
  __shared__ u16 Vs[128 * VLD];
  __shared__ u16 Ps[64 * PLD];
  const int p = (int)blockIdx.x;
  const int xcd = p & 7, j = p >> 3;
  const int bh = xcd * 4 + (j & 3);   // 4 bh per XCD
  const int pr = j >> 2;              // 0..15
  const int b = bh >> 4, h = bh & 15;
  const int bT = b * T_;
  const int tid = threadIdx.x, w = tid >> 6, lane = tid & 63;
  const int llo = lane & 15, lhi = lane >> 4;
  const u16* Vb = Vt + (size_t)bh * DV_ * T_;

  // per-thread K staging sources, swizzle pre-folded into source (rule #21)
  const u16* kbase[6]; int kstr[6];
#pragma unroll
  for (int ii = 0; ii < 6; ++ii) {
    int c = ii * 256 + tid;            // 1536 chunks = 64 rows x 24 chunks
    int rr = c / 24, chk = c - rr * 24;
    int sc = chk ^ (rr & 7);           // source chunk for linear LDS slot
    if (sc < 16) { kbase[ii] = kv + (size_t)(bT + rr) * 4096 + h * 256 + sc * 8; kstr[ii] = 4096; }
    else { kbase[ii] = kvraw + (size_t)(bT + rr) * AW_ + 2048 + h * 64 + (sc - 16) * 8; kstr[ii] = AW_; }
  }
  int voff[4];
#pragma unroll
  for (int ii = 0; ii < 4; ++ii) {
    int c = ii * 256 + tid;            // 1024 chunks = 128 d-rows x 8 chunks
    int rr = c >> 3, chk = c & 7;
    voff[ii] = rr * T_ + (chk ^ (rr & 7)) * 8;
  }

#pragma unroll
  for (int pass = 0; pass < 2; ++pass) {
    const int qt = pass == 0 ? 31 - pr : pr;
    const int q0 = qt * 64;
    const int rbase = q0 + w * 16;
    short8 qf[6];
#pragma unroll
    for (int kk = 0; kk < 6; ++kk)
      qf[kk] = *(const short8*)&q[(size_t)(bT + rbase + llo) * AW_ + h * DQK_ + kk * 32 + lhi * 8];
    f32x4 oacc[8] = {};
    float m_r[4], l_r[4];
#pragma unroll
    for (int r = 0; r < 4; ++r) { m_r[r] = -1e30f; l_r[r] = 0.f; }

    // prologue: stage K[0] into Ks[0]
#pragma unroll
    for (int ii = 0; ii < 6; ++ii)
      load_lds16(kbase[ii], &Ks[0][(ii * 256 + tid) * 8]);
    asm volatile("s_waitcnt vmcnt(0)" ::: "memory");
    __builtin_amdgcn_s_barrier();
    __builtin_amdgcn_sched_barrier(0);

    const int nkt = qt + 1;
    int cur = 0;
    for (int kt = 0; kt < nkt; ++kt) {
      const int k0 = kt * 64;
      const bool hasNext = (kt + 1 < nkt);
      // issue V[kt] -> Vs
#pragma unroll
      for (int ii = 0; ii < 4; ++ii)
        load_lds16(Vb + k0 + voff[ii], &Vs[(ii * 256 + tid) * 8]);
      // issue K[kt+1] -> other buffer
      if (hasNext) {
        u16* kd = Ks[cur ^ 1];
#pragma unroll
        for (int ii = 0; ii < 6; ++ii)
          load_lds16(kbase[ii] + (size_t)(k0 + 64) * kstr[ii], &kd[(ii * 256 + tid) * 8]);
      }
      // S = Q K^T from Ks[cur]
      const u16* kbuf = Ks[cur];
      f32x4 s[4] = {};
      __builtin_amdgcn_s_setprio(1);
#pragma unroll
      for (int kk = 0; kk < 6; ++kk) {
        const int col = kk * 32 + lhi * 8;
        short8 kf[4];
#pragma unroll
        for (int j2 = 0; j2 < 4; ++j2) {
          const int row = j2 * 16 + llo;
          kf[j2] = *(const short8*)&kbuf[row * KLD + (col ^ ((row & 7) << 3))];
        }
#pragma unroll
        for (int j2 = 0; j2 < 4; ++j2)
          s[j2] = __builtin_amdgcn_mfma_f32_16x16x32_bf16(qf[kk], kf[j2], s[j2], 0, 0, 0);
      }
      __builtin_amdgcn_s_setprio(0);
      // online softmax (exp2 domain; Q pre-scaled by log2e/sqrt(192))
      const bool needMask = (k0 + 63 > rbase);
#pragma unroll
      for (int r = 0; r < 4; ++r) {
        const int qrow = rbase + lhi * 4 + r;
        float sv[4];
#pragma unroll
        for (int j2 = 0; j2 < 4; ++j2) {
          float x = s[j2][r];
          if (needMask) { int kcol = k0 + j2 * 16 + llo; x = (kcol <= qrow) ? x : -1e30f; }
          sv[j2] = x;
        }
        // lazy row-max (defer-max T13): lane-local bound check first; the
        // cross-lane max + rescale only when some lane exceeds m+8.
        float mx4 = fmaxf(fmaxf(sv[0], sv[1]), fmaxf(sv[2], sv[3]));
        if (!__all(mx4 - m_r[r] <= 8.f)) {
          float mx = mx4;
#pragma unroll
          for (int mk = 1; mk < 16; mk <<= 1) mx = fmaxf(mx, __shfl_xor(mx, mk));
          float mnew = fmaxf(m_r[r], mx);
          float alpha = exp2f(m_r[r] - mnew);
          m_r[r] = mnew;
          l_r[r] *= alpha;
#pragma unroll
          for (int jo = 0; jo < 8; ++jo) oacc[jo][r] *= alpha;
        }
        float rs = 0.f;
        const int prow = w * 16 + lhi * 4 + r;
#pragma unroll
        for (int j2 = 0; j2 < 4; ++j2) {
          float p2 = exp2f(sv[j2] - m_r[r]);   // bounded by 2^8
          rs += p2;
          int pcol = j2 * 16 + llo;
          Ps[prow * PLD + (pcol ^ ((prow & 7) << 3))] = f2bf(p2);
        }
        l_r[r] += rs;   // per-lane partial; cross-lane reduce in epilogue
      }
      // V staged? (counted: leave the 6 K loads in flight)
      if (hasNext) asm volatile("s_waitcnt vmcnt(6)" ::: "memory");
      else         asm volatile("s_waitcnt vmcnt(0)" ::: "memory");
      __builtin_amdgcn_s_barrier();
      __builtin_amdgcn_sched_barrier(0);
      // PV (wave-local P rows; same-wave LDS RAW ordered by lgkmcnt)
      __builtin_amdgcn_s_setprio(1);
#pragma unroll
      for (int kk2 = 0; kk2 < 2; ++kk2) {
        const int prow = w * 16 + llo;
        const int pcol = kk2 * 32 + lhi * 8;
        short8 pf = *(const short8*)&Ps[prow * PLD + (pcol ^ ((prow & 7) << 3))];
#pragma unroll
        for (int jo = 0; jo < 8; ++jo) {
          const int vrow = jo * 16 + llo;
          short8 vf = *(const short8*)&Vs[vrow * VLD + (pcol ^ ((vrow & 7) << 3))];
          oacc[jo] = __builtin_amdgcn_mfma_f32_16x16x32_bf16(pf, vf, oacc[jo], 0, 0, 0);
        }
      }
      __builtin_amdgcn_s_setprio(0);
      // end of tile: K[t+1] landed; all waves done with Vs & Ks[cur]
      asm volatile("s_waitcnt vmcnt(0)" ::: "memory");
      __builtin_amdgcn_s_barrier();
      __builtin_amdgcn_sched_barrier(0);
      cur ^= 1;
    }
    // epilogue: reduce l partials across 16-lane group, store
#pragma unroll
    for (int r = 0; r < 4; ++r) {
      float lr = l_r[r];
#pragma unroll
      for (int mk = 1; mk < 16; mk <<= 1) lr += __shfl_xor(lr, mk);
      const int qrow = rbase + lhi * 4 + r;
      const float linv = 1.f / lr;
#pragma unroll
      for (int jo = 0; jo < 8; ++jo)
        att[((size_t)bT + qrow) * (H_ * DV_) + h * DV_ + jo * 16 + llo] =
            f2bf(oacc[jo][r] * linv);
    }
  }
}

// ---------------- launch ----------------
extern "C" void kernel_launch(void* const* d_in, const int* in_sizes, int n_in,
                              void* d_out, int out_size, void* d_ws, size_t ws_size,
                              hipStream_t stream) {
  const float* hs      = (const float*)d_in[0];
  const float* q_a_w   = (const float*)d_in[1];
  const float* q_a_ln  = (const float*)d_in[2];
  const float* q_b_w   = (const float*)d_in[3];
  const float* kv_a_w  = (const float*)d_in[4];
  const float* kv_a_ln = (const float*)d_in[5];
  const float* kv_b_w  = (const float*)d_in[6];
  const float* o_w     = (const float*)d_in[7];
  float* out = (float*)d_out;
  char* ws = (char*)d_ws;

  u16* hid  = (u16*)(ws + 0);          // 16.78 MB  (B*T, 2048) bf16
  u16* wt   = (u16*)(ws + 16777216);   // 12.58 MB  transposed weight (reused)
  u16* qa   = (u16*)(ws + 29360128);   // 25.17 MB  fused a-out: [q_a 1536 | kv_raw 1536]
  u16* qan  = (u16*)(ws + 54525952);   // 12.58 MB  q_a normed / later kv_latent
  u16* qout = (u16*)(ws + 67108864);   // 25.17 MB  q (B*T, 16*192), pre-scaled
  u16* att  = (u16*)(ws + 92274688);   // 16.78 MB  attn out (B*T, 2048)
  u16* kv   = (u16*)(ws + 109051904);  // 33.55 MB  kv_b out (k_nope|v per head)
  u16* Vt   = (u16*)(ws + 142606336);  // 16.78 MB  (B,H,128,T)

  cast_f32_bf16<<<4096, 256, 0, stream>>>(hs, hid);

  // fused a-proj: [q_a | kv_raw] = hid @ [q_a_w | kv_a_w]
  transpose_cast_k<<<dim3(1536 / 32, 2048 / 32), 256, 0, stream>>>(q_a_w, wt, 2048, 1536);
  transpose_cast_k<<<dim3(1536 / 32, 2048 / 32), 256, 0, stream>>>(kv_a_w, wt + (size_t)1536 * 2048, 2048, 1536);
  gemm_bt<1><<<(3072 / 128) * (4096 / 128), 256, 0, stream>>>(hid, wt, qa, 4096, 3072, 2048);

  // rmsnorm q_a -> qan
  rmsnorm_k<<<4096, 256, 0, stream>>>(qa, AW_, 1536, q_a_ln, qan, 1536);

  // q = qan @ q_b_w  (bf16, pre-scaled by log2e/sqrt(192))
  transpose_cast_k<<<dim3(3072 / 32, 1536 / 32), 256, 0, stream>>>(q_b_w, wt, 1536, 3072);
  gemm_bt<3><<<(3072 / 128) * (4096 / 128), 256, 0, stream>>>(qan, wt, qout, 4096, 3072, 1536);

  // rmsnorm kv latent (kv_raw = qa cols 1536..3071) -> qan (stride 512)
  rmsnorm_k<<<4096, 256, 0, stream>>>(qa + 1536, AW_, 512, kv_a_ln, qan, 512);

  // kv = kv_latent @ kv_b_w
  transpose_cast_k<<<dim3(4096 / 32, 512 / 32), 256, 0, stream>>>(kv_b_w, wt, 512, 4096);
  gemm_bt<1><<<(4096 / 128) * (4096 / 128), 256, 0, stream>>>(qan, wt, kv, 4096, 4096, 512);

  // V repack only (K staged in-place by attn from kv + qa)
  pack_vt_k<<<1024, 256, 0, stream>>>(kv, Vt);

  // attention -> att   (512 blocks, XCD-grouped bh, balanced 33-tile blocks)
  attn_k<<<512, 256, 0, stream>>>(qout, kv, qa, Vt, att);

  // out = att @ o_w
  transpose_cast_k<<<dim3(2048 / 32, 2048 / 32), 256, 0, stream>>>(o_w, wt, 2048, 2048);
  gemm_bt<0><<<(2048 / 128) * (4096 / 128), 256, 0, stream>>>(att, wt, out, 4096, 2048, 2048);
}